// Round 6
// baseline (167.025 us; speedup 1.0000x reference)
//
#include <hip/hip_runtime.h>

#define NN 100000
#define NE 1000000
#define OUT_D 64
#define EPS 1e-5f

#define NB 196          // buckets of 512 destination cols: 196*512 = 100352 >= NN
#define COLS 512
#define BSTRIDE 6016    // per-bucket raw capacity: mean 5120, +12.6 sigma
#define PBSTRIDE 8064   // padded bucket capacity = 4 * QCAP_PL
#define EPB 1024        // edges per part-block (small -> high block count, latency hiding)
#define NBLK1 977       // part blocks = ceil(NE/EPB)
#define NPROJ 1024      // proj blocks

#define QCOLS 128       // cols per place block (bucket quarter)
#define QCAP_PL 2016    // padded per-quarter capacity: mean ~1470 padded, ~15 sigma

#define WSTRIDE 136     // LDS W stride in halves: 272B, 16B-aligned, even bank spread

typedef __attribute__((ext_vector_type(8))) short bf16x8;
typedef __attribute__((ext_vector_type(4))) float f32x4;
typedef __attribute__((ext_vector_type(4))) int i32x4;

static __device__ __forceinline__ unsigned short f2bf(float f) {   // RNE
    unsigned u = __float_as_uint(f);
    u += 0x7FFFu + ((u >> 16) & 1u);
    return (unsigned short)(u >> 16);
}
static __device__ __forceinline__ float bf2f(unsigned short s) {
    return __uint_as_float((unsigned)s << 16);
}

// ---- partition: bucket-sort edges by dst/512 into gbuf (LDS-staged) --------
__global__ __launch_bounds__(256) void part_kernel(
    const int* __restrict__ ei, int* __restrict__ gcur, unsigned* __restrict__ gbuf)
{
    __shared__ int lcnt[NB];
    __shared__ int loff[NB + 1];
    __shared__ int lbase[NB];
    __shared__ int lcur[NB];
    __shared__ int wpart[4];
    __shared__ unsigned lbuf[EPB];
    __shared__ unsigned char lbkt[EPB];
    const int tid = threadIdx.x;
    const int lane = tid & 63;
    const int wv = tid >> 6;
    const int e0 = blockIdx.x * EPB;

    int rows[4], cols[4];
    #pragma unroll
    for (int j = 0; j < 4; ++j) {
        const int e = e0 + j * 256 + tid;
        const bool v = e < NE;
        rows[j] = v ? ei[e] : 0;
        cols[j] = v ? ei[NE + e] : -1;
    }
    for (int i = tid; i < NB; i += 256) lcnt[i] = 0;
    __syncthreads();
    #pragma unroll
    for (int j = 0; j < 4; ++j)
        if (cols[j] >= 0) atomicAdd(&lcnt[cols[j] >> 9], 1);
    __syncthreads();
    {   // block exclusive scan over NB bucket counts
        const int c = (tid < NB) ? lcnt[tid] : 0;
        int s = c;
        #pragma unroll
        for (int o = 1; o < 64; o <<= 1) { int t = __shfl_up(s, o); if (lane >= o) s += t; }
        if (lane == 63) wpart[wv] = s;
        __syncthreads();
        int woff = 0;
        for (int ww = 0; ww < wv; ++ww) woff += wpart[ww];
        if (tid < NB) {
            loff[tid] = woff + s - c;
            lcur[tid] = woff + s - c;
            lbase[tid] = atomicAdd(&gcur[tid], c);
        }
        if (tid == NB - 1) loff[NB] = woff + s;
    }
    __syncthreads();
    #pragma unroll
    for (int j = 0; j < 4; ++j) {
        if (cols[j] >= 0) {
            const int b = cols[j] >> 9;
            const int p = atomicAdd(&lcur[b], 1);
            lbuf[p] = ((unsigned)rows[j] << 9) | (unsigned)(cols[j] & (COLS - 1));
            lbkt[p] = (unsigned char)b;
        }
    }
    __syncthreads();
    const int total = loff[NB];
    for (int t = tid; t < total; t += 256) {
        const int b = lbkt[t];
        const unsigned idx = (unsigned)(lbase[b] + (t - loff[b]));
        if (idx < BSTRIDE) gbuf[(size_t)b * BSTRIDE + idx] = lbuf[t];
    }
}

// ---- proj: [y1|y2] = x @ [W1|W2] via MFMA (m89 layouts), W staged in LDS ---
__global__ __launch_bounds__(256) void proj_kernel(
    const float* __restrict__ x, const float* __restrict__ W,
    unsigned short* __restrict__ y1, unsigned short* __restrict__ y2)
{
    __shared__ __align__(16) unsigned short wlds[64 * WSTRIDE];   // [col][krow]
    const int tid = threadIdx.x;
    const int lane = tid & 63;
    const int wv = tid >> 6;

    if (blockIdx.x == 0 && tid < OUT_D)
        y2[(size_t)NN * OUT_D + tid] = 0;   // zeros row for pad gathers

    for (int i = tid; i < 128 * 64; i += 256) {     // stage W -> LDS (bf16, W^T)
        const int krow = i >> 6, col = i & 63;
        wlds[col * WSTRIDE + krow] = f2bf(W[i]);
    }
    __syncthreads();
    const int m = lane & 15;
    const int quad = lane >> 4;
    bf16x8 Wf[8][2];
    #pragma unroll
    for (int t = 0; t < 8; ++t)
        #pragma unroll
        for (int q = 0; q < 2; ++q) {
            const int krow0 = q * 32 + quad * 8 + ((t < 4) ? 0 : 64);
            const int col = (t & 3) * 16 + m;
            Wf[t][q] = *(const bf16x8*)(wlds + col * WSTRIDE + krow0);  // ds_read_b128
        }
    for (int tile = blockIdx.x * 4 + wv; tile < NN / 16; tile += NPROJ * 4) {
        const int n0 = tile * 16;
        bf16x8 Af[2];
        #pragma unroll
        for (int q = 0; q < 2; ++q) {
            const float* px = x + (size_t)(n0 + m) * 64 + q * 32 + quad * 8;
            const f32x4 a0 = *(const f32x4*)px;
            const f32x4 a1 = *(const f32x4*)(px + 4);
            bf16x8 f;
            #pragma unroll
            for (int j = 0; j < 4; ++j) { f[j] = (short)f2bf(a0[j]); f[4 + j] = (short)f2bf(a1[j]); }
            Af[q] = f;
        }
        #pragma unroll
        for (int t = 0; t < 8; ++t) {
            f32x4 acc = {0.f, 0.f, 0.f, 0.f};
            acc = __builtin_amdgcn_mfma_f32_16x16x32_bf16(Af[0], Wf[t][0], acc, 0, 0, 0);
            acc = __builtin_amdgcn_mfma_f32_16x16x32_bf16(Af[1], Wf[t][1], acc, 0, 0, 0);
            unsigned short* __restrict__ dst = (t < 4) ? y1 : y2;
            const int colb = (t & 3) * 16 + m;
            #pragma unroll
            for (int r = 0; r < 4; ++r)
                dst[(size_t)(n0 + quad * 4 + r) * 64 + colb] = f2bf(acc[r]);
        }
    }
}

// ---- per-quarter padded CSR build: 784 blocks, segments 4-aligned ----------
__global__ __launch_bounds__(256) void place_kernel(
    const int* __restrict__ gcur, const unsigned* __restrict__ gbuf,
    int* __restrict__ csr, unsigned* __restrict__ rowpack)
{
    __shared__ int cofs[QCOLS + 1];   // padded exclusive scan (inclusive at end)
    __shared__ int ccur[QCOLS];
    __shared__ int ccnt[QCOLS];
    __shared__ int ldst[QCAP_PL];
    const int tid = threadIdx.x;
    const int b = blockIdx.x >> 2;        // bucket
    const int q = blockIdx.x & 3;         // quarter within bucket

    const int cntE = min(gcur[b], BSTRIDE);
    const unsigned* __restrict__ gb = gbuf + (size_t)b * BSTRIDE;

    for (int i = tid; i < QCOLS; i += 256) ccnt[i] = 0;
    for (int i = tid; i < QCAP_PL; i += 256) ldst[i] = NN;   // pad = zeros row
    __syncthreads();
    for (int i = tid; i < cntE; i += 256) {               // pass 1: histogram
        const unsigned p = gb[i];
        const unsigned c9 = p & 511u;
        if ((int)(c9 >> 7) == q) atomicAdd(&ccnt[c9 & (QCOLS - 1)], 1);
    }
    __syncthreads();
    if (tid < 64) {   // single-wave exclusive scan of 128 PAD4 counts (2/lane)
        int v0 = (ccnt[2 * tid] + 3) & ~3;
        int v1 = (ccnt[2 * tid + 1] + 3) & ~3;
        const int tsum = v0 + v1;
        int s = tsum;
        #pragma unroll
        for (int o = 1; o < 64; o <<= 1) { int t = __shfl_up(s, o); if (tid >= o) s += t; }
        int run = s - tsum;
        cofs[2 * tid] = run;     ccur[2 * tid] = run;     run += v0;
        cofs[2 * tid + 1] = run; ccur[2 * tid + 1] = run; run += v1;
        if (tid == 63) cofs[QCOLS] = run;
    }
    __syncthreads();
    for (int i = tid; i < cntE; i += 256) {               // pass 2: scatter
        const unsigned p = gb[i];
        const unsigned c9 = p & 511u;
        if ((int)(c9 >> 7) == q) {
            const int pos = atomicAdd(&ccur[c9 & (QCOLS - 1)], 1);
            if (pos < QCAP_PL) ldst[pos] = (int)(p >> 9);
        }
    }
    __syncthreads();
    const int ptotal = min(cofs[QCOLS], QCAP_PL);
    const int base = b * PBSTRIDE + q * QCAP_PL;
    for (int i = tid; i < ptotal; i += 256) csr[base + i] = ldst[i];   // coalesced
    const int n0 = (b << 9) + (q << 7);
    for (int c = tid; c < QCOLS; c += 256) {
        const int n = n0 + c;
        if (n >= NN) continue;
        const int st = min(cofs[c], QCAP_PL);
        const int len = min(min(cofs[c + 1], QCAP_PL) - st, 511);
        rowpack[n] = ((unsigned)(q * QCAP_PL + st) << 9) | (unsigned)len;
    }
}

// ---- out: one node per wave; padded csr (dwordx4), 8 gathers in flight ----
__global__ __launch_bounds__(256) void out_kernel(
    const unsigned* __restrict__ rowpack, const int* __restrict__ csr,
    const unsigned short* __restrict__ y1, const unsigned short* __restrict__ y2,
    const float* __restrict__ bias, const float* __restrict__ gamma,
    const float* __restrict__ beta, float* __restrict__ out)
{
    const int lane = threadIdx.x & 63;
    const int n = __builtin_amdgcn_readfirstlane(blockIdx.x * 4 + (threadIdx.x >> 6));
    const unsigned pk = rowpack[n];
    const int cnt = (int)(pk & 511);                       // multiple of 4
    const i32x4* __restrict__ cs =
        (const i32x4*)(csr + (n >> 9) * PBSTRIDE + (int)(pk >> 9));

    float acc = bf2f(y1[(size_t)n * OUT_D + lane]) + bias[lane];
    int i = 0;
    for (; i + 8 <= cnt; i += 8) {                         // 8 gathers in flight
        const i32x4 c0 = cs[(i >> 2)];
        const i32x4 c1 = cs[(i >> 2) + 1];
        const float v0 = bf2f(y2[(size_t)c0[0] * OUT_D + lane]);
        const float v1 = bf2f(y2[(size_t)c0[1] * OUT_D + lane]);
        const float v2 = bf2f(y2[(size_t)c0[2] * OUT_D + lane]);
        const float v3 = bf2f(y2[(size_t)c0[3] * OUT_D + lane]);
        const float v4 = bf2f(y2[(size_t)c1[0] * OUT_D + lane]);
        const float v5 = bf2f(y2[(size_t)c1[1] * OUT_D + lane]);
        const float v6 = bf2f(y2[(size_t)c1[2] * OUT_D + lane]);
        const float v7 = bf2f(y2[(size_t)c1[3] * OUT_D + lane]);
        acc += ((v0 + v1) + (v2 + v3)) + ((v4 + v5) + (v6 + v7));
    }
    if (i < cnt) {                                         // exactly 4 left
        const i32x4 c0 = cs[(i >> 2)];
        const float v0 = bf2f(y2[(size_t)c0[0] * OUT_D + lane]);
        const float v1 = bf2f(y2[(size_t)c0[1] * OUT_D + lane]);
        const float v2 = bf2f(y2[(size_t)c0[2] * OUT_D + lane]);
        const float v3 = bf2f(y2[(size_t)c0[3] * OUT_D + lane]);
        acc += (v0 + v1) + (v2 + v3);
    }

    float sv = acc, sq = acc * acc;
    #pragma unroll
    for (int off = 32; off; off >>= 1) { sv += __shfl_xor(sv, off); sq += __shfl_xor(sq, off); }
    const float mu  = sv * (1.0f / OUT_D);
    const float var = sq * (1.0f / OUT_D) - mu * mu;
    const float inv = rsqrtf(var + EPS);
    out[(size_t)n * OUT_D + lane] = (acc - mu) * inv * gamma[lane] + beta[lane];
}

extern "C" void kernel_launch(void* const* d_in, const int* in_sizes, int n_in,
                              void* d_out, int out_size, void* d_ws, size_t ws_size,
                              hipStream_t stream) {
    const float* x     = (const float*)d_in[0];
    const int*   ei    = (const int*)  d_in[1];
    const float* W     = (const float*)d_in[2];
    const float* b     = (const float*)d_in[3];
    const float* gamma = (const float*)d_in[4];
    const float* beta  = (const float*)d_in[5];
    float* out = (float*)d_out;

    char* p = (char*)d_ws;
    int*            gcur    = (int*)p;             p += 1024;
    unsigned*       gbuf    = (unsigned*)p;        p += (size_t)NB * BSTRIDE * 4;   // 4.72 MB
    int*            csr     = (int*)p;             p += (size_t)NB * PBSTRIDE * 4;  // 6.32 MB
    unsigned*       rowpack = (unsigned*)p;        p += (size_t)(NB * COLS) * 4;    // 0.4 MB
    unsigned short* y1      = (unsigned short*)p;  p += (size_t)NN * OUT_D * 2;     // 12.8 MB
    unsigned short* y2      = (unsigned short*)p;                                   // 12.8 MB + zero row

    hipMemsetAsync(gcur, 0, NB * sizeof(int), stream);
    part_kernel <<<NBLK1, 256, 0, stream>>>(ei, gcur, gbuf);
    proj_kernel <<<NPROJ, 256, 0, stream>>>(x, W, y1, y2);
    place_kernel<<<NB * 4, 256, 0, stream>>>(gcur, gbuf, csr, rowpack);
    out_kernel  <<<NN / 4, 256, 0, stream>>>(rowpack, csr, y1, y2, b, gamma, beta, out);
}

// Round 7
// 133.276 us; speedup vs baseline: 1.2532x; 1.2532x over previous
//
#include <hip/hip_runtime.h>

#define NN 100000
#define NE 1000000
#define OUT_D 64
#define EPS 1e-5f

#define NB 196          // buckets of 512 destination cols: 196*512 = 100352 >= NN
#define COLS 512
#define BSTRIDE 6016    // per-bucket raw capacity: mean 5120, +12.6 sigma
#define PBSTRIDE 8064   // padded bucket capacity (pad4 segments)
#define EPB 4096        // edges per part-block
#define NBLK1 245       // part blocks = ceil(NE/EPB)
#define NPROJ 1024      // proj blocks fused behind part

#define NOUTB 2048      // persistent out blocks (8/CU, full occupancy)

#define WSTRIDE 136     // LDS W stride in halves: 272B, 16B-aligned, even bank spread

typedef __attribute__((ext_vector_type(8))) short bf16x8;
typedef __attribute__((ext_vector_type(4))) float f32x4;
typedef __attribute__((ext_vector_type(4))) int i32x4;

static __device__ __forceinline__ unsigned short f2bf(float f) {   // RNE
    unsigned u = __float_as_uint(f);
    u += 0x7FFFu + ((u >> 16) & 1u);
    return (unsigned short)(u >> 16);
}
static __device__ __forceinline__ float bf2f(unsigned short s) {
    return __uint_as_float((unsigned)s << 16);
}

// ---- mega kernel: blocks [0,NBLK1) partition edges; [NBLK1,..) do MFMA proj
// (R3 known-good: fused so partition latency hides under proj occupancy)
__global__ __launch_bounds__(256) void mega_kernel(
    const float* __restrict__ x, const float* __restrict__ W,
    const int* __restrict__ ei, int* __restrict__ gcur, unsigned* __restrict__ gbuf,
    unsigned short* __restrict__ y1, unsigned short* __restrict__ y2)
{
    __shared__ __align__(16) char smem[23648];
    const int tid = threadIdx.x;
    const int lane = tid & 63;
    const int wv = tid >> 6;

    if (blockIdx.x < NBLK1) {
        // ---------------- partition by dst-bucket (LDS-staged) ----------------
        int*           lcnt  = (int*)smem;                       // 784 B
        int*           loff  = (int*)(smem + 784);               // 788 B
        int*           lbase = (int*)(smem + 1572);              // 784 B
        int*           lcur  = (int*)(smem + 2356);              // 784 B
        int*           wpart = (int*)(smem + 3140);              // 16 B
        unsigned*      lbuf  = (unsigned*)(smem + 3156);         // 16384 B
        unsigned char* lbkt  = (unsigned char*)(smem + 19540);   // 4096 B
        const int e0 = blockIdx.x * EPB;

        int rows[16], cols[16];
        #pragma unroll
        for (int j = 0; j < 16; ++j) {
            const int e = e0 + j * 256 + tid;
            const bool v = e < NE;
            rows[j] = v ? ei[e] : 0;
            cols[j] = v ? ei[NE + e] : -1;
        }
        for (int i = tid; i < NB; i += 256) lcnt[i] = 0;
        __syncthreads();
        #pragma unroll
        for (int j = 0; j < 16; ++j)
            if (cols[j] >= 0) atomicAdd(&lcnt[cols[j] >> 9], 1);
        __syncthreads();
        {   // block exclusive scan over NB bucket counts
            const int c = (tid < NB) ? lcnt[tid] : 0;
            int s = c;
            #pragma unroll
            for (int o = 1; o < 64; o <<= 1) { int t = __shfl_up(s, o); if (lane >= o) s += t; }
            if (lane == 63) wpart[wv] = s;
            __syncthreads();
            int woff = 0;
            for (int ww = 0; ww < wv; ++ww) woff += wpart[ww];
            if (tid < NB) {
                loff[tid] = woff + s - c;
                lcur[tid] = woff + s - c;
                lbase[tid] = atomicAdd(&gcur[tid], c);
            }
            if (tid == NB - 1) loff[NB] = woff + s;
        }
        __syncthreads();
        #pragma unroll
        for (int j = 0; j < 16; ++j) {
            if (cols[j] >= 0) {
                const int b = cols[j] >> 9;
                const int p = atomicAdd(&lcur[b], 1);
                lbuf[p] = ((unsigned)rows[j] << 9) | (unsigned)(cols[j] & (COLS - 1));
                lbkt[p] = (unsigned char)b;
            }
        }
        __syncthreads();
        const int total = loff[NB];
        for (int t = tid; t < total; t += 256) {   // ~21-word coalesced bursts
            const int b = lbkt[t];
            const unsigned idx = (unsigned)(lbase[b] + (t - loff[b]));
            if (idx < BSTRIDE) gbuf[(size_t)b * BSTRIDE + idx] = lbuf[t];
        }
    } else {
        // ---------------- [y1|y2] = x @ [W1|W2] via MFMA (m89 layouts) --------
        if (blockIdx.x == NBLK1 && tid < OUT_D)
            y2[(size_t)NN * OUT_D + tid] = 0;   // zeros row for pad gathers
        unsigned short* wlds = (unsigned short*)smem;   // [64 cols][WSTRIDE rows]
        for (int i = tid; i < 128 * 64; i += 256) {     // stage W -> LDS (bf16, W^T)
            const int krow = i >> 6, col = i & 63;
            wlds[col * WSTRIDE + krow] = f2bf(W[i]);
        }
        __syncthreads();
        const int m = lane & 15;
        const int quad = lane >> 4;
        bf16x8 Wf[8][2];
        #pragma unroll
        for (int t = 0; t < 8; ++t)
            #pragma unroll
            for (int q = 0; q < 2; ++q) {
                const int krow0 = q * 32 + quad * 8 + ((t < 4) ? 0 : 64);
                const int col = (t & 3) * 16 + m;
                Wf[t][q] = *(const bf16x8*)(wlds + col * WSTRIDE + krow0);  // ds_read_b128
            }
        for (int tile = (blockIdx.x - NBLK1) * 4 + wv; tile < NN / 16; tile += NPROJ * 4) {
            const int n0 = tile * 16;
            bf16x8 Af[2];
            #pragma unroll
            for (int q = 0; q < 2; ++q) {
                const float* px = x + (size_t)(n0 + m) * 64 + q * 32 + quad * 8;
                const f32x4 a0 = *(const f32x4*)px;
                const f32x4 a1 = *(const f32x4*)(px + 4);
                bf16x8 f;
                #pragma unroll
                for (int j = 0; j < 4; ++j) { f[j] = (short)f2bf(a0[j]); f[4 + j] = (short)f2bf(a1[j]); }
                Af[q] = f;
            }
            #pragma unroll
            for (int t = 0; t < 8; ++t) {
                f32x4 acc = {0.f, 0.f, 0.f, 0.f};
                acc = __builtin_amdgcn_mfma_f32_16x16x32_bf16(Af[0], Wf[t][0], acc, 0, 0, 0);
                acc = __builtin_amdgcn_mfma_f32_16x16x32_bf16(Af[1], Wf[t][1], acc, 0, 0, 0);
                unsigned short* __restrict__ dst = (t < 4) ? y1 : y2;
                const int colb = (t & 3) * 16 + m;
                #pragma unroll
                for (int r = 0; r < 4; ++r)
                    dst[(size_t)(n0 + quad * 4 + r) * 64 + colb] = f2bf(acc[r]);
            }
        }
    }
}

// ---- full-bucket padded CSR build: 196 blocks x 512 thr (halved atomic chains)
__global__ __launch_bounds__(512) void place_kernel(
    const int* __restrict__ gcur, const unsigned* __restrict__ gbuf,
    int* __restrict__ csr, unsigned* __restrict__ rowpack)
{
    __shared__ int cofs[COLS + 1];   // histogram, then padded exclusive scan
    __shared__ int ccur[COLS];
    __shared__ unsigned lsrc[BSTRIDE];
    __shared__ int ldst[PBSTRIDE];
    const int b = blockIdx.x, tid = threadIdx.x;
    const int n0 = b << 9;

    for (int i = tid; i < COLS; i += 512) cofs[i] = 0;
    for (int i = tid; i < PBSTRIDE; i += 512) ldst[i] = NN;     // pad = zeros row
    __syncthreads();
    const int cntE = min(gcur[b], BSTRIDE);
    const unsigned* __restrict__ gb = gbuf + (size_t)b * BSTRIDE;

    for (int i = tid; i < cntE; i += 512) {    // stage + histogram (single pass)
        const unsigned p = gb[i];
        lsrc[i] = p;
        atomicAdd(&cofs[p & (COLS - 1)], 1);
    }
    __syncthreads();
    if (tid < 64) {   // single-wave exclusive scan of 512 PAD4 counts (8/lane)
        int v[8], tsum = 0;
        #pragma unroll
        for (int k = 0; k < 8; ++k) { v[k] = (cofs[tid * 8 + k] + 3) & ~3; tsum += v[k]; }
        int s = tsum;
        #pragma unroll
        for (int o = 1; o < 64; o <<= 1) { int t = __shfl_up(s, o); if (tid >= o) s += t; }
        int run = s - tsum;
        #pragma unroll
        for (int k = 0; k < 8; ++k) { cofs[tid * 8 + k] = run; ccur[tid * 8 + k] = run; run += v[k]; }
        if (tid == 63) cofs[COLS] = run;
    }
    __syncthreads();
    for (int i = tid; i < cntE; i += 512) {    // place rows (LDS scatter)
        const unsigned p = lsrc[i];
        const int pos = atomicAdd(&ccur[p & (COLS - 1)], 1);
        ldst[pos] = (int)(p >> 9);
    }
    __syncthreads();
    const int ptotal = cofs[COLS];
    const int base = b * PBSTRIDE;
    for (int i = tid; i < ptotal; i += 512) csr[base + i] = ldst[i];   // coalesced
    const int ncols = min(COLS, NN - n0);
    for (int c = tid; c < ncols; c += 512) {
        const int st = cofs[c];
        const int len = min(cofs[c + 1] - st, 511);
        rowpack[n0 + c] = ((unsigned)st << 9) | (unsigned)len;
    }
}

// ---- out: persistent grid-stride, one node per wave per iter; 8 gathers in flight
__global__ __launch_bounds__(256) void out_kernel(
    const unsigned* __restrict__ rowpack, const int* __restrict__ csr,
    const unsigned short* __restrict__ y1, const unsigned short* __restrict__ y2,
    const float* __restrict__ bias, const float* __restrict__ gamma,
    const float* __restrict__ beta, float* __restrict__ out)
{
    const int lane = threadIdx.x & 63;
    const int wid0 = __builtin_amdgcn_readfirstlane(blockIdx.x * 4 + (threadIdx.x >> 6));
    const float bi = bias[lane], ga = gamma[lane], be = beta[lane];

    for (int n = wid0; n < NN; n += NOUTB * 4) {
        const unsigned pk = rowpack[n];
        const int cnt = (int)(pk & 511);                       // multiple of 4
        const i32x4* __restrict__ cs =
            (const i32x4*)(csr + (n >> 9) * PBSTRIDE + (int)(pk >> 9));

        float acc = bf2f(y1[(size_t)n * OUT_D + lane]) + bi;
        int i = 0;
        for (; i + 8 <= cnt; i += 8) {                         // 8 gathers in flight
            const i32x4 c0 = cs[(i >> 2)];
            const i32x4 c1 = cs[(i >> 2) + 1];
            const float v0 = bf2f(y2[(size_t)c0[0] * OUT_D + lane]);
            const float v1 = bf2f(y2[(size_t)c0[1] * OUT_D + lane]);
            const float v2 = bf2f(y2[(size_t)c0[2] * OUT_D + lane]);
            const float v3 = bf2f(y2[(size_t)c0[3] * OUT_D + lane]);
            const float v4 = bf2f(y2[(size_t)c1[0] * OUT_D + lane]);
            const float v5 = bf2f(y2[(size_t)c1[1] * OUT_D + lane]);
            const float v6 = bf2f(y2[(size_t)c1[2] * OUT_D + lane]);
            const float v7 = bf2f(y2[(size_t)c1[3] * OUT_D + lane]);
            acc += ((v0 + v1) + (v2 + v3)) + ((v4 + v5) + (v6 + v7));
        }
        if (i < cnt) {                                         // exactly 4 left
            const i32x4 c0 = cs[(i >> 2)];
            const float v0 = bf2f(y2[(size_t)c0[0] * OUT_D + lane]);
            const float v1 = bf2f(y2[(size_t)c0[1] * OUT_D + lane]);
            const float v2 = bf2f(y2[(size_t)c0[2] * OUT_D + lane]);
            const float v3 = bf2f(y2[(size_t)c0[3] * OUT_D + lane]);
            acc += (v0 + v1) + (v2 + v3);
        }

        float sv = acc, sq = acc * acc;
        #pragma unroll
        for (int off = 32; off; off >>= 1) { sv += __shfl_xor(sv, off); sq += __shfl_xor(sq, off); }
        const float mu  = sv * (1.0f / OUT_D);
        const float var = sq * (1.0f / OUT_D) - mu * mu;
        const float inv = rsqrtf(var + EPS);
        out[(size_t)n * OUT_D + lane] = (acc - mu) * inv * ga + be;
    }
}

extern "C" void kernel_launch(void* const* d_in, const int* in_sizes, int n_in,
                              void* d_out, int out_size, void* d_ws, size_t ws_size,
                              hipStream_t stream) {
    const float* x     = (const float*)d_in[0];
    const int*   ei    = (const int*)  d_in[1];
    const float* W     = (const float*)d_in[2];
    const float* b     = (const float*)d_in[3];
    const float* gamma = (const float*)d_in[4];
    const float* beta  = (const float*)d_in[5];
    float* out = (float*)d_out;

    char* p = (char*)d_ws;
    int*            gcur    = (int*)p;             p += 1024;
    unsigned*       gbuf    = (unsigned*)p;        p += (size_t)NB * BSTRIDE * 4;   // 4.72 MB
    int*            csr     = (int*)p;             p += (size_t)NB * PBSTRIDE * 4;  // 6.32 MB
    unsigned*       rowpack = (unsigned*)p;        p += (size_t)(NB * COLS) * 4;    // 0.4 MB
    unsigned short* y1      = (unsigned short*)p;  p += (size_t)NN * OUT_D * 2;     // 12.8 MB
    unsigned short* y2      = (unsigned short*)p;                                   // 12.8 MB + zero row

    hipMemsetAsync(gcur, 0, NB * sizeof(int), stream);
    mega_kernel <<<NBLK1 + NPROJ, 256, 0, stream>>>(x, W, ei, gcur, gbuf, y1, y2);
    place_kernel<<<NB, 512, 0, stream>>>(gcur, gbuf, csr, rowpack);
    out_kernel  <<<NOUTB, 256, 0, stream>>>(rowpack, csr, y1, y2, b, gamma, beta, out);
}